// Round 17
// baseline (194.796 us; speedup 1.0000x reference)
//
#include <hip/hip_runtime.h>
#include <math.h>

#define D 512
#define H 8
#define DH 64
#define S 4096
#define FF 1024

typedef __attribute__((ext_vector_type(8))) short bf16x8;
typedef __attribute__((ext_vector_type(4))) float f32x4;
typedef __attribute__((ext_vector_type(16))) float f32x16;

__device__ __forceinline__ unsigned short f2bf(float f) {
    union { float f; unsigned u; } c; c.f = f;
    unsigned r = (c.u + 0x7fff + ((c.u >> 16) & 1)) >> 16;
    return (unsigned short)r;
}
__device__ __forceinline__ float bf2f(unsigned short u) {
    union { unsigned u; float f; } c; c.u = ((unsigned)u) << 16;
    return c.f;
}

// async global->LDS 16B copy (direct-to-LDS DMA; LDS dst = wave-uniform base + lane*16)
__device__ __forceinline__ void gl_lds16(const void* g, void* l) {
    __builtin_amdgcn_global_load_lds(
        (const __attribute__((address_space(1))) void*)g,
        (__attribute__((address_space(3))) void*)l, 16, 0, 0);
}

// ------------- prep: weight transposes (blocks 0..2047) + LN1 (blocks 2048..6143) ---
__global__ __launch_bounds__(256) void prep_kernel(const float* __restrict__ wqkv,
                                                   const float* __restrict__ wout,
                                                   const float* __restrict__ wff1,
                                                   const float* __restrict__ wff2,
                                                   unsigned short* __restrict__ oqkv,
                                                   unsigned short* __restrict__ oout,
                                                   unsigned short* __restrict__ off1,
                                                   unsigned short* __restrict__ off2,
                                                   const float* __restrict__ x,
                                                   const float* __restrict__ g1,
                                                   const float* __restrict__ bt1,
                                                   unsigned short* __restrict__ hout) {
    __shared__ unsigned short tile[32][33];
    __shared__ float red[8];
    int id = blockIdx.x;
    int tid = threadIdx.x;
    if (id >= 2048) {
        int row = id - 2048;
        const float* xr = x + (size_t)row * D;
        float2 v = *(const float2*)(xr + tid * 2);
        float s = v.x + v.y;
        float sq = v.x * v.x + v.y * v.y;
#pragma unroll
        for (int m = 1; m < 64; m <<= 1) { s += __shfl_xor(s, m); sq += __shfl_xor(sq, m); }
        int wave = tid >> 6, lane = tid & 63;
        if (lane == 0) { red[wave] = s; red[4 + wave] = sq; }
        __syncthreads();
        s = red[0] + red[1] + red[2] + red[3];
        sq = red[4] + red[5] + red[6] + red[7];
        float mu = s * (1.f / D);
        float var = sq * (1.f / D) - mu * mu;
        float rstd = rsqrtf(var + 1e-5f);
        int i = tid * 2;
        float2 gg = *(const float2*)(g1 + i);
        float2 bb = *(const float2*)(bt1 + i);
        hout[(size_t)row * D + i]     = f2bf((v.x - mu) * rstd * gg.x + bb.x);
        hout[(size_t)row * D + i + 1] = f2bf((v.y - mu) * rstd * gg.y + bb.y);
        return;
    }
    const float* src; unsigned short* dst; int K, N, lid;
    if (id < 768)       { src = wqkv; dst = oqkv; K = 512;  N = 1536; lid = id; }
    else if (id < 1024) { src = wout; dst = oout; K = 512;  N = 512;  lid = id - 768; }
    else if (id < 1536) { src = wff1; dst = off1; K = 512;  N = 1024; lid = id - 1024; }
    else                { src = wff2; dst = off2; K = 1024; N = 512;  lid = id - 1536; }
    int nb = N / 32;
    int n0 = (lid % nb) * 32, k0 = (lid / nb) * 32;
    int tx = tid & 31, ty = tid >> 5;
#pragma unroll
    for (int i = 0; i < 32; i += 8)
        tile[ty + i][tx] = f2bf(src[(size_t)(k0 + ty + i) * N + n0 + tx]);
    __syncthreads();
#pragma unroll
    for (int i = 0; i < 32; i += 8)
        dst[(size_t)(n0 + ty + i) * K + k0 + tx] = tile[tx][ty + i];
}

// ---------------- layernorm: fp32 [rows][512] -> bf16, one block per row -----------
__global__ __launch_bounds__(256) void ln_kernel(const float* __restrict__ x,
                                                 const float* __restrict__ g,
                                                 const float* __restrict__ bta,
                                                 unsigned short* __restrict__ out) {
    int row = blockIdx.x, tid = threadIdx.x;
    const float* xr = x + (size_t)row * D;
    float2 v = *(const float2*)(xr + tid * 2);
    float s = v.x + v.y;
    float sq = v.x * v.x + v.y * v.y;
#pragma unroll
    for (int m = 1; m < 64; m <<= 1) { s += __shfl_xor(s, m); sq += __shfl_xor(sq, m); }
    __shared__ float red[8];
    int wave = tid >> 6, lane = tid & 63;
    if (lane == 0) { red[wave] = s; red[4 + wave] = sq; }
    __syncthreads();
    s = red[0] + red[1] + red[2] + red[3];
    sq = red[4] + red[5] + red[6] + red[7];
    float mu = s * (1.f / D);
    float var = sq * (1.f / D) - mu * mu;
    float rstd = rsqrtf(var + 1e-5f);
    int i = tid * 2;
    float2 gg = *(const float2*)(g + i);
    float2 bb = *(const float2*)(bta + i);
    out[(size_t)row * D + i]     = f2bf((v.x - mu) * rstd * gg.x + bb.x);
    out[(size_t)row * D + i + 1] = f2bf((v.y - mu) * rstd * gg.y + bb.y);
}

// ---------------- GEMM v5 (QKV): BK=64 dbuf DMA prefetch, never-drain vmcnt ---------
enum { EPI_BF16 = 0, EPI_RESID_F32 = 1, EPI_GELU_BF16 = 2 };

template <int EPI, int WMI, int BNT, bool QKV>
__global__ __launch_bounds__(256, WMI == 4 ? 2 : (WMI == 2 ? 3 : 4))
void gemm5_kernel(const unsigned short* __restrict__ A,
                  const unsigned short* __restrict__ BT,
                  const float* __restrict__ bias,
                  const float* __restrict__ resid,
                  void* __restrict__ out,
                  unsigned short* __restrict__ vTout,
                  int M, int N, int K) {
    constexpr int BM = 32 * WMI;
    constexpr int APH = BM / 32;
    constexpr int BPH = BNT / 32;
    constexpr int NLD = APH + BPH;
    constexpr int NI = BNT / 32;
    __shared__ __align__(16) unsigned short sA[2][BM * 64];
    __shared__ __align__(16) unsigned short sB[2][BNT * 64];

    int tid = threadIdx.x;
    int wave = tid >> 6, lane = tid & 63;
    int quad = lane >> 4, l16 = lane & 15;
    int lx = l16 & 7;
    int wr = (wave >> 1) * (BM / 2), wc = (wave & 1) * (BNT / 2);
    int m0 = blockIdx.y * BM, n0 = blockIdx.x * BNT;

    f32x4 acc[WMI][NI];
#pragma unroll
    for (int i = 0; i < WMI; i++)
#pragma unroll
        for (int j = 0; j < NI; j++) acc[i][j] = (f32x4){0.f, 0.f, 0.f, 0.f};

    int srow = tid >> 3;
    int spc = tid & 7;
    int scc = spc ^ (srow & 7);
    const unsigned short* Abase = A + (size_t)(m0 + srow) * K + scc * 8;
    const unsigned short* Bbase = BT + (size_t)(n0 + srow) * K + scc * 8;
    int wofs = (tid & ~63) * 8;

    auto stage = [&](int k0, int buf) {
#pragma unroll
        for (int ph = 0; ph < APH; ph++)
            gl_lds16(Abase + (size_t)(ph * 32) * K + k0, sA[buf] + wofs + ph * 2048);
#pragma unroll
        for (int ph = 0; ph < BPH; ph++)
            gl_lds16(Bbase + (size_t)(ph * 32) * K + k0, sB[buf] + wofs + ph * 2048);
    };

    int nk = K / 64;
    stage(0, 0);
    for (int ki = 0; ki < nk; ki++) {
        int buf = ki & 1;
        if (ki + 1 < nk) {
            stage((ki + 1) * 64, buf ^ 1);
            if constexpr (NLD == 3)
                asm volatile("s_waitcnt vmcnt(3)" ::: "memory");
            else if constexpr (NLD == 4)
                asm volatile("s_waitcnt vmcnt(4)" ::: "memory");
            else if constexpr (NLD == 6)
                asm volatile("s_waitcnt vmcnt(6)" ::: "memory");
            else
                asm volatile("s_waitcnt vmcnt(8)" ::: "memory");
        } else {
            asm volatile("s_waitcnt vmcnt(0)" ::: "memory");
        }
        __syncthreads();

#pragma unroll
        for (int ks = 0; ks < 2; ks++) {
            int cxs = ((ks * 4 + quad) ^ lx) * 8;
            bf16x8 af[WMI], bfr[NI];
#pragma unroll
            for (int mi = 0; mi < WMI; mi++)
                af[mi] = *(const bf16x8*)(&sA[buf][(wr + mi * 16 + l16) * 64 + cxs]);
#pragma unroll
            for (int ni = 0; ni < NI; ni++)
                bfr[ni] = *(const bf16x8*)(&sB[buf][(wc + ni * 16 + l16) * 64 + cxs]);
#pragma unroll
            for (int mi = 0; mi < WMI; mi++)
#pragma unroll
                for (int ni = 0; ni < NI; ni++)
                    acc[mi][ni] = __builtin_amdgcn_mfma_f32_16x16x32_bf16(af[mi], bfr[ni], acc[mi][ni], 0, 0, 0);
        }
        __syncthreads();
    }

#pragma unroll
    for (int mi = 0; mi < WMI; mi++)
#pragma unroll
        for (int ni = 0; ni < NI; ni++) {
            int col = n0 + wc + ni * 16 + l16;
            float bs = bias[col];
            int row0 = m0 + wr + mi * 16 + quad * 4;
            unsigned short tv[4];
#pragma unroll
            for (int r = 0; r < 4; r++) {
                float v = acc[mi][ni][r] + bs;
                size_t idx = (size_t)(row0 + r) * N + col;
                if constexpr (EPI == EPI_RESID_F32) {
                    ((float*)out)[idx] = v + resid[idx];
                } else if constexpr (EPI == EPI_GELU_BF16) {
                    v = 0.5f * v * (1.f + erff(v * 0.70710678118f));
                    ((unsigned short*)out)[idx] = f2bf(v);
                } else {
                    unsigned short b = f2bf(v);
                    ((unsigned short*)out)[idx] = b;
                    tv[r] = b;
                }
            }
            if constexpr (QKV) {
                if (col >= 2 * D) {
                    unsigned lo = (unsigned)tv[0] | ((unsigned)tv[1] << 16);
                    unsigned hi = (unsigned)tv[2] | ((unsigned)tv[3] << 16);
                    uint2 pk; pk.x = lo; pk.y = hi;
                    *(uint2*)(vTout + (size_t)(col - 2 * D) * S + row0) = pk;
                }
            }
        }
}

// ---------------- GEMM v6 (narrow): BM=32/BN=64/BK=128 — half the serial chain ------
// Latency-bound K-loop: wall ~ n_iters x exposed latency. BK=128 halves iterations
// (K=512: 4, K=1024: 8) at the cost of 48KB LDS (3 blocks/CU vs 4). 16-chunk XOR
// swizzle (slot = chunk ^ (row&15)); 6 DMA phases/tile, never-drain vmcnt(6).
template <int EPI>
__global__ __launch_bounds__(256, 3)
void gemm6_kernel(const unsigned short* __restrict__ A,
                  const unsigned short* __restrict__ BT,
                  const float* __restrict__ bias,
                  const float* __restrict__ resid,
                  void* __restrict__ out,
                  int M, int N, int K) {
    __shared__ __align__(16) unsigned short sA[2][32 * 128];
    __shared__ __align__(16) unsigned short sB[2][64 * 128];

    int tid = threadIdx.x;
    int wave = tid >> 6, lane = tid & 63;
    int quad = lane >> 4, l16 = lane & 15;
    int wr = (wave >> 1) * 16, wc = (wave & 1) * 32;
    int m0 = blockIdx.y * 32, n0 = blockIdx.x * 64;

    f32x4 acc[2];
    acc[0] = (f32x4){0.f, 0.f, 0.f, 0.f};
    acc[1] = (f32x4){0.f, 0.f, 0.f, 0.f};

    // staging: 16 rows x 16 chunks per phase-call; slot spc holds global chunk scc
    int srow = tid >> 4;               // 0..15
    int spc = tid & 15;
    int scc = spc ^ srow;              // row&15 == srow for every phase
    const unsigned short* Abase = A + (size_t)(m0 + srow) * K + scc * 8;
    const unsigned short* Bbase = BT + (size_t)(n0 + srow) * K + scc * 8;
    int wofs = (tid & ~63) * 8;        // wave-uniform LDS base (shorts)

    auto stage = [&](int k0, int buf) {
#pragma unroll
        for (int ph = 0; ph < 2; ph++)   // A: 32 rows in 2 phases of 16
            gl_lds16(Abase + (size_t)(ph * 16) * K + k0, sA[buf] + wofs + ph * 2048);
#pragma unroll
        for (int ph = 0; ph < 4; ph++)   // B: 64 rows in 4 phases of 16
            gl_lds16(Bbase + (size_t)(ph * 16) * K + k0, sB[buf] + wofs + ph * 2048);
    };

    int nk = K / 128;
    stage(0, 0);
    for (int ki = 0; ki < nk; ki++) {
        int buf = ki & 1;
        if (ki + 1 < nk) {
            stage((ki + 1) * 128, buf ^ 1);
            asm volatile("s_waitcnt vmcnt(6)" ::: "memory");  // tile ki done; ki+1 in flight
        } else {
            asm volatile("s_waitcnt vmcnt(0)" ::: "memory");
        }
        __syncthreads();

#pragma unroll
        for (int ks = 0; ks < 4; ks++) {
            int cxs = ((ks * 4 + quad) ^ l16) * 8;   // slot = chunk ^ (row&15)
            bf16x8 af = *(const bf16x8*)(&sA[buf][(wr + l16) * 128 + cxs]);
#pragma unroll
            for (int ni = 0; ni < 2; ni++) {
                bf16x8 bfr = *(const bf16x8*)(&sB[buf][(wc + ni * 16 + l16) * 128 + cxs]);
                acc[ni] = __builtin_amdgcn_mfma_f32_16x16x32_bf16(af, bfr, acc[ni], 0, 0, 0);
            }
        }
        __syncthreads();
    }

#pragma unroll
    for (int ni = 0; ni < 2; ni++) {
        int col = n0 + wc + ni * 16 + l16;
        float bs = bias[col];
        int row0 = m0 + wr + quad * 4;
#pragma unroll
        for (int r = 0; r < 4; r++) {
            float v = acc[ni][r] + bs;
            size_t idx = (size_t)(row0 + r) * N + col;
            if constexpr (EPI == EPI_RESID_F32) {
                ((float*)out)[idx] = v + resid[idx];
            } else if constexpr (EPI == EPI_GELU_BF16) {
                v = 0.5f * v * (1.f + erff(v * 0.70710678118f));
                ((unsigned short*)out)[idx] = f2bf(v);
            } else {
                ((unsigned short*)out)[idx] = f2bf(v);
            }
        }
    }
}

// ---------------- flash attention v8 (best-known): 2-buffer DMA, vmcnt(0) -----------
#define LDO 68   // epilogue O-transpose rows

__global__ __launch_bounds__(256, 4) void flash8_kernel(const unsigned short* __restrict__ qkv,
                                                        const unsigned short* __restrict__ vT,
                                                        unsigned short* __restrict__ O_part,
                                                        float* __restrict__ l_part) {
    __shared__ __align__(16) unsigned short sMem[4][64 * 64];

    int tid = threadIdx.x;
    int w = tid >> 6, lane = tid & 63;
    int lq = lane & 31, hb = lane >> 5;

    int h = blockIdx.x & 7;
    int u = blockIdx.x >> 3;
    int Q = 31, c = 0, acc = 0;
    for (int qq = 31; qq >= 0; --qq) {
        int n = (qq >> 2) + 1;
        if (u < acc + n) { Q = qq; c = u - acc; break; }
        acc += n;
    }
    int T = 2 * Q + 2;
    int t0c = c * 8;
    int t1c = min(t0c + 8, T);
    int q0w = Q * 128 + w * 32;
    int qrow = q0w + lq;
    int qmax = q0w + 31;

    const float CEXP = 0.18033688f;   // log2(e)/sqrt(DH)

    bf16x8 qf[4];
#pragma unroll
    for (int dc = 0; dc < 4; dc++)
        qf[dc] = *(const bf16x8*)(qkv + (size_t)qrow * (3 * D) + h * DH + dc * 16 + hb * 8);

    f32x16 oa[2];
#pragma unroll
    for (int i = 0; i < 16; i++) { oa[0][i] = 0.f; oa[1][i] = 0.f; }
    float l4[4] = {0.f, 0.f, 0.f, 0.f};

    int rr = tid >> 3;
    int spc = tid & 7;
    int scc = spc ^ (rr & 7);
    const unsigned short* kgb = qkv + (size_t)rr * (3 * D) + D + h * DH + scc * 8;
    const unsigned short* vgb = vT + (size_t)(h * DH + rr) * S + scc * 8;

    auto stage = [&](int t, int buf) {
        const unsigned short* kg = kgb + (size_t)t * 64 * (3 * D);
        const unsigned short* vg = vgb + t * 64;
        unsigned short* dK = sMem[buf] + w * 512;
        unsigned short* dV = sMem[2 + buf] + w * 512;
        gl_lds16(kg, dK);
        gl_lds16(kg + (size_t)32 * (3 * D), dK + 2048);
        gl_lds16(vg, dV);
        gl_lds16(vg + (size_t)32 * S, dV + 2048);
    };

    stage(t0c, 0);
    for (int t = t0c; t < t1c; ++t) {
        int buf = (t - t0c) & 1;
        asm volatile("s_waitcnt vmcnt(0)" ::: "memory");
        __syncthreads();
        if (t + 1 < t1c) stage(t + 1, buf ^ 1);

        if (64 * t > qmax) continue;

        f32x16 sa[2];
#pragma unroll
        for (int i = 0; i < 16; i++) { sa[0][i] = 0.f; sa[1][i] = 0.f; }
#pragma unroll
        for (int kt = 0; kt < 2; kt++)
#pragma unroll
            for (int dc = 0; dc < 4; dc++) {
                int ch = ((dc * 2 + hb) ^ (lq & 7)) * 8;
                bf16x8 kfr = *(const bf16x8*)(&sMem[buf][(kt * 32 + lq) * 64 + ch]);
                sa[kt] = __builtin_amdgcn_mfma_f32_32x32x16_bf16(kfr, qf[dc], sa[kt], 0, 0, 0);
            }

        bool dmask = (64 * t + 63 > qmax);
        unsigned p2[2][8];
        if (!dmask) {
#pragma unroll
            for (int kt = 0; kt < 2; kt++) {
                float e[16];
#pragma unroll
                for (int r = 0; r < 16; r++) {
                    e[r] = __builtin_amdgcn_exp2f(sa[kt][r] * CEXP);
                    l4[r & 3] += e[r];
                }
#pragma unroll
                for (int p = 0; p < 8; p++)
                    p2[kt][p] = ((unsigned)f2bf(e[2 * p + 1]) << 16) | f2bf(e[2 * p]);
            }
        } else {
#pragma unroll
            for (int kt = 0; kt < 2; kt++) {
                float e[16];
#pragma unroll
                for (int r = 0; r < 16; r++) {
                    float v = __builtin_amdgcn_exp2f(sa[kt][r] * CEXP);
                    int key = 64 * t + kt * 32 + (r & 3) + 8 * (r >> 2) + 4 * hb;
                    if (key > qrow) v = 0.f;
                    e[r] = v;
                    l4[r & 3] += v;
                }
#pragma unroll
                for (int p = 0; p < 8; p++)
                    p2[kt][p] = ((unsigned)f2bf(e[2 * p + 1]) << 16) | f2bf(e[2 * p]);
            }
        }

#pragma unroll
        for (int kc = 0; kc < 4; kc++) {
            int kt = kc >> 1;
            int b0i = (kc & 1) * 4;
            unsigned a0 = p2[kt][b0i + 0], a1 = p2[kt][b0i + 1];
            unsigned b0 = p2[kt][b0i + 2], b1 = p2[kt][b0i + 3];
            unsigned s0 = hb ? a0 : b0, s1 = hb ? a1 : b1;
            unsigned x0 = __shfl_xor(s0, 32), x1 = __shfl_xor(s1, 32);
            unsigned l0 = hb ? b0 : a0, l1 = hb ? b1 : a1;
            union { unsigned u[4]; bf16x8 v; } fr;
            fr.u[0] = hb ? x0 : l0;
            fr.u[1] = hb ? x1 : l1;
            fr.u[2] = hb ? l0 : x0;
            fr.u[3] = hb ? l1 : x1;
#pragma unroll
            for (int dt = 0; dt < 2; dt++) {
                int ch = ((kc * 2 + hb) ^ (lq & 7)) * 8;
                bf16x8 vfr = *(const bf16x8*)(&sMem[2 + buf][(dt * 32 + lq) * 64 + ch]);
                oa[dt] = __builtin_amdgcn_mfma_f32_32x32x16_bf16(vfr, fr.v, oa[dt], 0, 0, 0);
            }
        }
    }

    float lsum = (l4[0] + l4[1]) + (l4[2] + l4[3]);
    lsum += __shfl_xor(lsum, 32);
    if (hb == 0)
        l_part[((size_t)c * H + h) * S + q0w + lq] = lsum;

    __syncthreads();
    unsigned short* sOw = (unsigned short*)sMem + w * 32 * LDO;
#pragma unroll
    for (int kt = 0; kt < 2; kt++)
#pragma unroll
        for (int r = 0; r < 16; r++) {
            int d = kt * 32 + (r & 3) + 8 * (r >> 2) + 4 * hb;
            sOw[lq * LDO + d] = f2bf(oa[kt][r]);
        }
    asm volatile("s_waitcnt lgkmcnt(0)" ::: "memory");
    unsigned short* Op = O_part + ((size_t)c * S + q0w) * D + h * DH;
#pragma unroll
    for (int it = 0; it < 4; it++) {
        int rq = (lane >> 3) + it * 8;
        bf16x8 val = *(const bf16x8*)(sOw + rq * LDO + (lane & 7) * 8);
        *(bf16x8*)(Op + (size_t)rq * D + (lane & 7) * 8) = val;
    }
}

// ---------------- merge partials (vectorized x8): O = sum O_part / sum l ------------
__global__ __launch_bounds__(256) void norm_kernel(const unsigned short* __restrict__ O_part,
                                                   const float* __restrict__ l_part,
                                                   unsigned short* __restrict__ O) {
    int idx = blockIdx.x * 256 + threadIdx.x;
    int row = idx >> 6;
    int c8 = (idx & 63) * 8;
    int h = c8 >> 6;
    int nch = ((row >> 7) >> 2) + 1;
    float o[8] = {0.f, 0.f, 0.f, 0.f, 0.f, 0.f, 0.f, 0.f};
    float l = 0.f;
    for (int cc = 0; cc < nch; cc++) {
        bf16x8 v = *(const bf16x8*)(O_part + ((size_t)cc * S + row) * D + c8);
#pragma unroll
        for (int j = 0; j < 8; j++) o[j] += bf2f((unsigned short)v[j]);
        l += l_part[((size_t)cc * H + h) * S + row];
    }
    float inv = 1.f / l;
    bf16x8 r;
#pragma unroll
    for (int j = 0; j < 8; j++) r[j] = (short)f2bf(o[j] * inv);
    *(bf16x8*)(O + (size_t)row * D + c8) = r;
}

// ---------------- launch ----------------
extern "C" void kernel_launch(void* const* d_in, const int* in_sizes, int n_in,
                              void* d_out, int out_size, void* d_ws, size_t ws_size,
                              hipStream_t stream) {
    const float* x     = (const float*)d_in[0];
    const float* w_qkv = (const float*)d_in[1];
    const float* b_qkv = (const float*)d_in[2];
    const float* w_out = (const float*)d_in[3];
    const float* b_out = (const float*)d_in[4];
    const float* w_ff1 = (const float*)d_in[5];
    const float* b_ff1 = (const float*)d_in[6];
    const float* w_ff2 = (const float*)d_in[7];
    const float* b_ff2 = (const float*)d_in[8];
    const float* g1    = (const float*)d_in[9];
    const float* bt1   = (const float*)d_in[10];
    const float* g2    = (const float*)d_in[11];
    const float* bt2   = (const float*)d_in[12];

    char* ws = (char*)d_ws;
    size_t off = 0;
    auto alloc = [&](size_t bytes) {
        void* p = ws + off;
        off += (bytes + 255) & ~(size_t)255;
        return p;
    };
    unsigned short* hbuf   = (unsigned short*)alloc((size_t)S * D * 2);
    unsigned short* qkvbuf = (unsigned short*)alloc((size_t)S * 3 * D * 2);
    unsigned short* vTbuf  = (unsigned short*)alloc((size_t)D * S * 2);
    unsigned short* Obuf   = (unsigned short*)alloc((size_t)S * D * 2);
    unsigned short* wqkvT  = (unsigned short*)alloc((size_t)3 * D * D * 2);
    unsigned short* woutT  = (unsigned short*)alloc((size_t)D * D * 2);
    unsigned short* wff1T  = (unsigned short*)alloc((size_t)FF * D * 2);
    unsigned short* wff2T  = (unsigned short*)alloc((size_t)D * FF * 2);
    unsigned short* Opart  = (unsigned short*)alloc((size_t)8 * S * D * 2);
    float*          lpart  = (float*)alloc((size_t)8 * H * S * 4);
    unsigned short* h2buf  = hbuf;              // reuse (LN2 out)
    unsigned short* ff1buf = qkvbuf;            // reuse (FF1 act)
    float*          x2buf  = (float*)Opart;     // alias: Opart dead after norm_kernel

    prep_kernel<<<dim3(2048 + S), 256, 0, stream>>>(w_qkv, w_out, w_ff1, w_ff2,
                                                    wqkvT, woutT, wff1T, wff2T,
                                                    x, g1, bt1, hbuf);
    gemm5_kernel<EPI_BF16, 2, 128, true><<<dim3(12, 64), 256, 0, stream>>>(
        hbuf, wqkvT, b_qkv, nullptr, qkvbuf, vTbuf, S, 3 * D, D);
    flash8_kernel<<<dim3(1152), 256, 0, stream>>>(qkvbuf, vTbuf, Opart, lpart);
    norm_kernel<<<dim3(S * D / 8 / 256), 256, 0, stream>>>(Opart, lpart, Obuf);
    gemm6_kernel<EPI_RESID_F32><<<dim3(8, 128), 256, 0, stream>>>(
        Obuf, woutT, b_out, x, x2buf, S, D, D);
    ln_kernel<<<S, 256, 0, stream>>>(x2buf, g2, bt2, h2buf);
    gemm6_kernel<EPI_GELU_BF16><<<dim3(16, 128), 256, 0, stream>>>(
        h2buf, wff1T, b_ff1, nullptr, ff1buf, S, FF, D);
    gemm6_kernel<EPI_RESID_F32><<<dim3(8, 128), 256, 0, stream>>>(
        ff1buf, wff2T, b_ff2, x2buf, (float*)d_out, S, D, FF);
}

// Round 18
// 187.289 us; speedup vs baseline: 1.0401x; 1.0401x over previous
//
#include <hip/hip_runtime.h>
#include <math.h>

#define D 512
#define H 8
#define DH 64
#define S 4096
#define FF 1024

typedef __attribute__((ext_vector_type(8))) short bf16x8;
typedef __attribute__((ext_vector_type(4))) float f32x4;
typedef __attribute__((ext_vector_type(16))) float f32x16;

__device__ __forceinline__ unsigned short f2bf(float f) {
    union { float f; unsigned u; } c; c.f = f;
    unsigned r = (c.u + 0x7fff + ((c.u >> 16) & 1)) >> 16;
    return (unsigned short)r;
}
__device__ __forceinline__ float bf2f(unsigned short u) {
    union { unsigned u; float f; } c; c.u = ((unsigned)u) << 16;
    return c.f;
}

// async global->LDS 16B copy (direct-to-LDS DMA; LDS dst = wave-uniform base + lane*16)
__device__ __forceinline__ void gl_lds16(const void* g, void* l) {
    __builtin_amdgcn_global_load_lds(
        (const __attribute__((address_space(1))) void*)g,
        (__attribute__((address_space(3))) void*)l, 16, 0, 0);
}

// ------------- prep: weight transposes (blocks 0..2047) + LN1 (blocks 2048..6143) ---
__global__ __launch_bounds__(256) void prep_kernel(const float* __restrict__ wqkv,
                                                   const float* __restrict__ wout,
                                                   const float* __restrict__ wff1,
                                                   const float* __restrict__ wff2,
                                                   unsigned short* __restrict__ oqkv,
                                                   unsigned short* __restrict__ oout,
                                                   unsigned short* __restrict__ off1,
                                                   unsigned short* __restrict__ off2,
                                                   const float* __restrict__ x,
                                                   const float* __restrict__ g1,
                                                   const float* __restrict__ bt1,
                                                   unsigned short* __restrict__ hout) {
    __shared__ unsigned short tile[32][33];
    __shared__ float red[8];
    int id = blockIdx.x;
    int tid = threadIdx.x;
    if (id >= 2048) {
        int row = id - 2048;
        const float* xr = x + (size_t)row * D;
        float2 v = *(const float2*)(xr + tid * 2);
        float s = v.x + v.y;
        float sq = v.x * v.x + v.y * v.y;
#pragma unroll
        for (int m = 1; m < 64; m <<= 1) { s += __shfl_xor(s, m); sq += __shfl_xor(sq, m); }
        int wave = tid >> 6, lane = tid & 63;
        if (lane == 0) { red[wave] = s; red[4 + wave] = sq; }
        __syncthreads();
        s = red[0] + red[1] + red[2] + red[3];
        sq = red[4] + red[5] + red[6] + red[7];
        float mu = s * (1.f / D);
        float var = sq * (1.f / D) - mu * mu;
        float rstd = rsqrtf(var + 1e-5f);
        int i = tid * 2;
        float2 gg = *(const float2*)(g1 + i);
        float2 bb = *(const float2*)(bt1 + i);
        hout[(size_t)row * D + i]     = f2bf((v.x - mu) * rstd * gg.x + bb.x);
        hout[(size_t)row * D + i + 1] = f2bf((v.y - mu) * rstd * gg.y + bb.y);
        return;
    }
    const float* src; unsigned short* dst; int K, N, lid;
    if (id < 768)       { src = wqkv; dst = oqkv; K = 512;  N = 1536; lid = id; }
    else if (id < 1024) { src = wout; dst = oout; K = 512;  N = 512;  lid = id - 768; }
    else if (id < 1536) { src = wff1; dst = off1; K = 512;  N = 1024; lid = id - 1024; }
    else                { src = wff2; dst = off2; K = 1024; N = 512;  lid = id - 1536; }
    int nb = N / 32;
    int n0 = (lid % nb) * 32, k0 = (lid / nb) * 32;
    int tx = tid & 31, ty = tid >> 5;
#pragma unroll
    for (int i = 0; i < 32; i += 8)
        tile[ty + i][tx] = f2bf(src[(size_t)(k0 + ty + i) * N + n0 + tx]);
    __syncthreads();
#pragma unroll
    for (int i = 0; i < 32; i += 8)
        dst[(size_t)(n0 + ty + i) * K + k0 + tx] = tile[tx][ty + i];
}

// ---------------- layernorm: fp32 [rows][512] -> bf16, one block per row -----------
__global__ __launch_bounds__(256) void ln_kernel(const float* __restrict__ x,
                                                 const float* __restrict__ g,
                                                 const float* __restrict__ bta,
                                                 unsigned short* __restrict__ out) {
    int row = blockIdx.x, tid = threadIdx.x;
    const float* xr = x + (size_t)row * D;
    float2 v = *(const float2*)(xr + tid * 2);
    float s = v.x + v.y;
    float sq = v.x * v.x + v.y * v.y;
#pragma unroll
    for (int m = 1; m < 64; m <<= 1) { s += __shfl_xor(s, m); sq += __shfl_xor(sq, m); }
    __shared__ float red[8];
    int wave = tid >> 6, lane = tid & 63;
    if (lane == 0) { red[wave] = s; red[4 + wave] = sq; }
    __syncthreads();
    s = red[0] + red[1] + red[2] + red[3];
    sq = red[4] + red[5] + red[6] + red[7];
    float mu = s * (1.f / D);
    float var = sq * (1.f / D) - mu * mu;
    float rstd = rsqrtf(var + 1e-5f);
    int i = tid * 2;
    float2 gg = *(const float2*)(g + i);
    float2 bb = *(const float2*)(bta + i);
    out[(size_t)row * D + i]     = f2bf((v.x - mu) * rstd * gg.x + bb.x);
    out[(size_t)row * D + i + 1] = f2bf((v.y - mu) * rstd * gg.y + bb.y);
}

// ---------------- GEMM v5: dbuf DMA prefetch, never-drain vmcnt, tunable BN ---------
enum { EPI_BF16 = 0, EPI_RESID_F32 = 1, EPI_GELU_BF16 = 2 };

template <int EPI, int WMI, int BNT, bool QKV>
__global__ __launch_bounds__(256, WMI == 4 ? 2 : (WMI == 2 ? 3 : 4))
void gemm5_kernel(const unsigned short* __restrict__ A,
                  const unsigned short* __restrict__ BT,
                  const float* __restrict__ bias,
                  const float* __restrict__ resid,
                  void* __restrict__ out,
                  unsigned short* __restrict__ vTout,
                  int M, int N, int K) {
    constexpr int BM = 32 * WMI;
    constexpr int APH = BM / 32;
    constexpr int BPH = BNT / 32;
    constexpr int NLD = APH + BPH;
    constexpr int NI = BNT / 32;
    __shared__ __align__(16) unsigned short sA[2][BM * 64];
    __shared__ __align__(16) unsigned short sB[2][BNT * 64];

    int tid = threadIdx.x;
    int wave = tid >> 6, lane = tid & 63;
    int quad = lane >> 4, l16 = lane & 15;
    int lx = l16 & 7;
    int wr = (wave >> 1) * (BM / 2), wc = (wave & 1) * (BNT / 2);
    int m0 = blockIdx.y * BM, n0 = blockIdx.x * BNT;

    f32x4 acc[WMI][NI];
#pragma unroll
    for (int i = 0; i < WMI; i++)
#pragma unroll
        for (int j = 0; j < NI; j++) acc[i][j] = (f32x4){0.f, 0.f, 0.f, 0.f};

    int srow = tid >> 3;
    int spc = tid & 7;
    int scc = spc ^ (srow & 7);
    const unsigned short* Abase = A + (size_t)(m0 + srow) * K + scc * 8;
    const unsigned short* Bbase = BT + (size_t)(n0 + srow) * K + scc * 8;
    int wofs = (tid & ~63) * 8;

    auto stage = [&](int k0, int buf) {
#pragma unroll
        for (int ph = 0; ph < APH; ph++)
            gl_lds16(Abase + (size_t)(ph * 32) * K + k0, sA[buf] + wofs + ph * 2048);
#pragma unroll
        for (int ph = 0; ph < BPH; ph++)
            gl_lds16(Bbase + (size_t)(ph * 32) * K + k0, sB[buf] + wofs + ph * 2048);
    };

    int nk = K / 64;
    stage(0, 0);
    for (int ki = 0; ki < nk; ki++) {
        int buf = ki & 1;
        if (ki + 1 < nk) {
            stage((ki + 1) * 64, buf ^ 1);
            if constexpr (NLD == 3)
                asm volatile("s_waitcnt vmcnt(3)" ::: "memory");
            else if constexpr (NLD == 4)
                asm volatile("s_waitcnt vmcnt(4)" ::: "memory");
            else if constexpr (NLD == 6)
                asm volatile("s_waitcnt vmcnt(6)" ::: "memory");
            else
                asm volatile("s_waitcnt vmcnt(8)" ::: "memory");
        } else {
            asm volatile("s_waitcnt vmcnt(0)" ::: "memory");
        }
        __syncthreads();

#pragma unroll
        for (int ks = 0; ks < 2; ks++) {
            int cxs = ((ks * 4 + quad) ^ lx) * 8;
            bf16x8 af[WMI], bfr[NI];
#pragma unroll
            for (int mi = 0; mi < WMI; mi++)
                af[mi] = *(const bf16x8*)(&sA[buf][(wr + mi * 16 + l16) * 64 + cxs]);
#pragma unroll
            for (int ni = 0; ni < NI; ni++)
                bfr[ni] = *(const bf16x8*)(&sB[buf][(wc + ni * 16 + l16) * 64 + cxs]);
#pragma unroll
            for (int mi = 0; mi < WMI; mi++)
#pragma unroll
                for (int ni = 0; ni < NI; ni++)
                    acc[mi][ni] = __builtin_amdgcn_mfma_f32_16x16x32_bf16(af[mi], bfr[ni], acc[mi][ni], 0, 0, 0);
        }
        __syncthreads();
    }

#pragma unroll
    for (int mi = 0; mi < WMI; mi++)
#pragma unroll
        for (int ni = 0; ni < NI; ni++) {
            int col = n0 + wc + ni * 16 + l16;
            float bs = bias[col];
            int row0 = m0 + wr + mi * 16 + quad * 4;
            unsigned short tv[4];
#pragma unroll
            for (int r = 0; r < 4; r++) {
                float v = acc[mi][ni][r] + bs;
                size_t idx = (size_t)(row0 + r) * N + col;
                if constexpr (EPI == EPI_RESID_F32) {
                    ((float*)out)[idx] = v + resid[idx];
                } else if constexpr (EPI == EPI_GELU_BF16) {
                    v = 0.5f * v * (1.f + erff(v * 0.70710678118f));
                    ((unsigned short*)out)[idx] = f2bf(v);
                } else {
                    unsigned short b = f2bf(v);
                    ((unsigned short*)out)[idx] = b;
                    tv[r] = b;
                }
            }
            if constexpr (QKV) {
                if (col >= 2 * D) {
                    unsigned lo = (unsigned)tv[0] | ((unsigned)tv[1] << 16);
                    unsigned hi = (unsigned)tv[2] | ((unsigned)tv[3] << 16);
                    uint2 pk; pk.x = lo; pk.y = hi;
                    *(uint2*)(vTout + (size_t)(col - 2 * D) * S + row0) = pk;
                }
            }
        }
}

// ---------------- flash attention v8 (best-known): 2-buffer DMA, vmcnt(0) -----------
// chunk=8 key-tiles, 1152 blocks (4/CU resident), stage AFTER barrier. Structural
// plateau confirmed R6-R17: pipelining depth, VALU diet, register prefetch, chunk
// size, occupancy push all flat or regressed; this variant is the measured floor.
#define LDO 68   // epilogue O-transpose rows

__global__ __launch_bounds__(256, 4) void flash8_kernel(const unsigned short* __restrict__ qkv,
                                                        const unsigned short* __restrict__ vT,
                                                        unsigned short* __restrict__ O_part,
                                                        float* __restrict__ l_part) {
    __shared__ __align__(16) unsigned short sMem[4][64 * 64];

    int tid = threadIdx.x;
    int w = tid >> 6, lane = tid & 63;
    int lq = lane & 31, hb = lane >> 5;

    int h = blockIdx.x & 7;
    int u = blockIdx.x >> 3;
    int Q = 31, c = 0, acc = 0;
    for (int qq = 31; qq >= 0; --qq) {
        int n = (qq >> 2) + 1;
        if (u < acc + n) { Q = qq; c = u - acc; break; }
        acc += n;
    }
    int T = 2 * Q + 2;
    int t0c = c * 8;
    int t1c = min(t0c + 8, T);
    int q0w = Q * 128 + w * 32;
    int qrow = q0w + lq;
    int qmax = q0w + 31;

    const float CEXP = 0.18033688f;   // log2(e)/sqrt(DH)

    bf16x8 qf[4];
#pragma unroll
    for (int dc = 0; dc < 4; dc++)
        qf[dc] = *(const bf16x8*)(qkv + (size_t)qrow * (3 * D) + h * DH + dc * 16 + hb * 8);

    f32x16 oa[2];
#pragma unroll
    for (int i = 0; i < 16; i++) { oa[0][i] = 0.f; oa[1][i] = 0.f; }
    float l4[4] = {0.f, 0.f, 0.f, 0.f};

    int rr = tid >> 3;
    int spc = tid & 7;
    int scc = spc ^ (rr & 7);
    const unsigned short* kgb = qkv + (size_t)rr * (3 * D) + D + h * DH + scc * 8;
    const unsigned short* vgb = vT + (size_t)(h * DH + rr) * S + scc * 8;

    auto stage = [&](int t, int buf) {
        const unsigned short* kg = kgb + (size_t)t * 64 * (3 * D);
        const unsigned short* vg = vgb + t * 64;
        unsigned short* dK = sMem[buf] + w * 512;
        unsigned short* dV = sMem[2 + buf] + w * 512;
        gl_lds16(kg, dK);
        gl_lds16(kg + (size_t)32 * (3 * D), dK + 2048);
        gl_lds16(vg, dV);
        gl_lds16(vg + (size_t)32 * S, dV + 2048);
    };

    stage(t0c, 0);
    for (int t = t0c; t < t1c; ++t) {
        int buf = (t - t0c) & 1;
        asm volatile("s_waitcnt vmcnt(0)" ::: "memory");
        __syncthreads();
        if (t + 1 < t1c) stage(t + 1, buf ^ 1);

        if (64 * t > qmax) continue;

        f32x16 sa[2];
#pragma unroll
        for (int i = 0; i < 16; i++) { sa[0][i] = 0.f; sa[1][i] = 0.f; }
#pragma unroll
        for (int kt = 0; kt < 2; kt++)
#pragma unroll
            for (int dc = 0; dc < 4; dc++) {
                int ch = ((dc * 2 + hb) ^ (lq & 7)) * 8;
                bf16x8 kfr = *(const bf16x8*)(&sMem[buf][(kt * 32 + lq) * 64 + ch]);
                sa[kt] = __builtin_amdgcn_mfma_f32_32x32x16_bf16(kfr, qf[dc], sa[kt], 0, 0, 0);
            }

        bool dmask = (64 * t + 63 > qmax);
        unsigned p2[2][8];
        if (!dmask) {
#pragma unroll
            for (int kt = 0; kt < 2; kt++) {
                float e[16];
#pragma unroll
                for (int r = 0; r < 16; r++) {
                    e[r] = __builtin_amdgcn_exp2f(sa[kt][r] * CEXP);
                    l4[r & 3] += e[r];
                }
#pragma unroll
                for (int p = 0; p < 8; p++)
                    p2[kt][p] = ((unsigned)f2bf(e[2 * p + 1]) << 16) | f2bf(e[2 * p]);
            }
        } else {
#pragma unroll
            for (int kt = 0; kt < 2; kt++) {
                float e[16];
#pragma unroll
                for (int r = 0; r < 16; r++) {
                    float v = __builtin_amdgcn_exp2f(sa[kt][r] * CEXP);
                    int key = 64 * t + kt * 32 + (r & 3) + 8 * (r >> 2) + 4 * hb;
                    if (key > qrow) v = 0.f;
                    e[r] = v;
                    l4[r & 3] += v;
                }
#pragma unroll
                for (int p = 0; p < 8; p++)
                    p2[kt][p] = ((unsigned)f2bf(e[2 * p + 1]) << 16) | f2bf(e[2 * p]);
            }
        }

#pragma unroll
        for (int kc = 0; kc < 4; kc++) {
            int kt = kc >> 1;
            int b0i = (kc & 1) * 4;
            unsigned a0 = p2[kt][b0i + 0], a1 = p2[kt][b0i + 1];
            unsigned b0 = p2[kt][b0i + 2], b1 = p2[kt][b0i + 3];
            unsigned s0 = hb ? a0 : b0, s1 = hb ? a1 : b1;
            unsigned x0 = __shfl_xor(s0, 32), x1 = __shfl_xor(s1, 32);
            unsigned l0 = hb ? b0 : a0, l1 = hb ? b1 : a1;
            union { unsigned u[4]; bf16x8 v; } fr;
            fr.u[0] = hb ? x0 : l0;
            fr.u[1] = hb ? x1 : l1;
            fr.u[2] = hb ? l0 : x0;
            fr.u[3] = hb ? l1 : x1;
#pragma unroll
            for (int dt = 0; dt < 2; dt++) {
                int ch = ((kc * 2 + hb) ^ (lq & 7)) * 8;
                bf16x8 vfr = *(const bf16x8*)(&sMem[2 + buf][(dt * 32 + lq) * 64 + ch]);
                oa[dt] = __builtin_amdgcn_mfma_f32_32x32x16_bf16(vfr, fr.v, oa[dt], 0, 0, 0);
            }
        }
    }

    float lsum = (l4[0] + l4[1]) + (l4[2] + l4[3]);
    lsum += __shfl_xor(lsum, 32);
    if (hb == 0)
        l_part[((size_t)c * H + h) * S + q0w + lq] = lsum;

    __syncthreads();
    unsigned short* sOw = (unsigned short*)sMem + w * 32 * LDO;
#pragma unroll
    for (int kt = 0; kt < 2; kt++)
#pragma unroll
        for (int r = 0; r < 16; r++) {
            int d = kt * 32 + (r & 3) + 8 * (r >> 2) + 4 * hb;
            sOw[lq * LDO + d] = f2bf(oa[kt][r]);
        }
    asm volatile("s_waitcnt lgkmcnt(0)" ::: "memory");
    unsigned short* Op = O_part + ((size_t)c * S + q0w) * D + h * DH;
#pragma unroll
    for (int it = 0; it < 4; it++) {
        int rq = (lane >> 3) + it * 8;
        bf16x8 val = *(const bf16x8*)(sOw + rq * LDO + (lane & 7) * 8);
        *(bf16x8*)(Op + (size_t)rq * D + (lane & 7) * 8) = val;
    }
}

// ---------------- merge partials (vectorized x8): O = sum O_part / sum l ------------
__global__ __launch_bounds__(256) void norm_kernel(const unsigned short* __restrict__ O_part,
                                                   const float* __restrict__ l_part,
                                                   unsigned short* __restrict__ O) {
    int idx = blockIdx.x * 256 + threadIdx.x;
    int row = idx >> 6;
    int c8 = (idx & 63) * 8;
    int h = c8 >> 6;
    int nch = ((row >> 7) >> 2) + 1;
    float o[8] = {0.f, 0.f, 0.f, 0.f, 0.f, 0.f, 0.f, 0.f};
    float l = 0.f;
    for (int cc = 0; cc < nch; cc++) {
        bf16x8 v = *(const bf16x8*)(O_part + ((size_t)cc * S + row) * D + c8);
#pragma unroll
        for (int j = 0; j < 8; j++) o[j] += bf2f((unsigned short)v[j]);
        l += l_part[((size_t)cc * H + h) * S + row];
    }
    float inv = 1.f / l;
    bf16x8 r;
#pragma unroll
    for (int j = 0; j < 8; j++) r[j] = (short)f2bf(o[j] * inv);
    *(bf16x8*)(O + (size_t)row * D + c8) = r;
}

// ---------------- launch ----------------
extern "C" void kernel_launch(void* const* d_in, const int* in_sizes, int n_in,
                              void* d_out, int out_size, void* d_ws, size_t ws_size,
                              hipStream_t stream) {
    const float* x     = (const float*)d_in[0];
    const float* w_qkv = (const float*)d_in[1];
    const float* b_qkv = (const float*)d_in[2];
    const float* w_out = (const float*)d_in[3];
    const float* b_out = (const float*)d_in[4];
    const float* w_ff1 = (const float*)d_in[5];
    const float* b_ff1 = (const float*)d_in[6];
    const float* w_ff2 = (const float*)d_in[7];
    const float* b_ff2 = (const float*)d_in[8];
    const float* g1    = (const float*)d_in[9];
    const float* bt1   = (const float*)d_in[10];
    const float* g2    = (const float*)d_in[11];
    const float* bt2   = (const float*)d_in[12];

    char* ws = (char*)d_ws;
    size_t off = 0;
    auto alloc = [&](size_t bytes) {
        void* p = ws + off;
        off += (bytes + 255) & ~(size_t)255;
        return p;
    };
    unsigned short* hbuf   = (unsigned short*)alloc((size_t)S * D * 2);
    unsigned short* qkvbuf = (unsigned short*)alloc((size_t)S * 3 * D * 2);
    unsigned short* vTbuf  = (unsigned short*)alloc((size_t)D * S * 2);
    unsigned short* Obuf   = (unsigned short*)alloc((size_t)S * D * 2);
    unsigned short* wqkvT  = (unsigned short*)alloc((size_t)3 * D * D * 2);
    unsigned short* woutT  = (unsigned short*)alloc((size_t)D * D * 2);
    unsigned short* wff1T  = (unsigned short*)alloc((size_t)FF * D * 2);
    unsigned short* wff2T  = (unsigned short*)alloc((size_t)D * FF * 2);
    unsigned short* Opart  = (unsigned short*)alloc((size_t)8 * S * D * 2);
    float*          lpart  = (float*)alloc((size_t)8 * H * S * 4);
    unsigned short* h2buf  = hbuf;              // reuse (LN2 out)
    unsigned short* ff1buf = qkvbuf;            // reuse (FF1 act)
    float*          x2buf  = (float*)Opart;     // alias: Opart dead after norm_kernel

    prep_kernel<<<dim3(2048 + S), 256, 0, stream>>>(w_qkv, w_out, w_ff1, w_ff2,
                                                    wqkvT, woutT, wff1T, wff2T,
                                                    x, g1, bt1, hbuf);
    gemm5_kernel<EPI_BF16, 2, 128, true><<<dim3(12, 64), 256, 0, stream>>>(
        hbuf, wqkvT, b_qkv, nullptr, qkvbuf, vTbuf, S, 3 * D, D);
    flash8_kernel<<<dim3(1152), 256, 0, stream>>>(qkvbuf, vTbuf, Opart, lpart);
    norm_kernel<<<dim3(S * D / 8 / 256), 256, 0, stream>>>(Opart, lpart, Obuf);
    gemm5_kernel<EPI_RESID_F32, 1, 64, false><<<dim3(8, 128), 256, 0, stream>>>(
        Obuf, woutT, b_out, x, x2buf, nullptr, S, D, D);
    ln_kernel<<<S, 256, 0, stream>>>(x2buf, g2, bt2, h2buf);
    gemm5_kernel<EPI_GELU_BF16, 1, 64, false><<<dim3(16, 128), 256, 0, stream>>>(
        h2buf, wff1T, b_ff1, nullptr, ff1buf, nullptr, S, FF, D);
    gemm5_kernel<EPI_RESID_F32, 1, 64, false><<<dim3(8, 128), 256, 0, stream>>>(
        ff1buf, wff2T, b_ff2, x2buf, (float*)d_out, nullptr, S, D, FF);
}